// Round 5
// baseline (318.233 us; speedup 1.0000x reference)
//
#include <hip/hip_runtime.h>
#include <hip/hip_bf16.h>
#include <stdint.h>

typedef __attribute__((ext_vector_type(4))) float f32x4;
typedef __attribute__((ext_vector_type(16))) float f32x16;
typedef __attribute__((ext_vector_type(8))) short bf16x8;
typedef __attribute__((ext_vector_type(4))) uint32_t u32x4;

#define KD 512
#define ND 512

// pack two fp32 -> one u32 of two bf16 (round-half-away via +0x8000; v_perm
// grabs the high 16 bits of each)
__device__ __forceinline__ uint32_t pk_bf16(float lo, float hi) {
  uint32_t ulo = __float_as_uint(lo) + 0x8000u;
  uint32_t uhi = __float_as_uint(hi) + 0x8000u;
  return __builtin_amdgcn_perm(uhi, ulo, 0x07060302u);
}

// Transpose + RNE-convert w (512x512 fp32, w[k][d]) -> wt[d][k] bf16 in d_ws.
__global__ void wt_kernel(const float* __restrict__ w, uint16_t* __restrict__ wt) {
  __shared__ float tile[32][33];
  const int bx = blockIdx.x, by = blockIdx.y;
  const int tx = threadIdx.x, ty = threadIdx.y;  // (32, 8)
#pragma unroll
  for (int i = 0; i < 32; i += 8)
    tile[ty + i][tx] = w[(bx * 32 + ty + i) * ND + by * 32 + tx];
  __syncthreads();
#pragma unroll
  for (int i = 0; i < 32; i += 8) {
    uint32_t u = __float_as_uint(tile[tx][ty + i]);
    uint32_t r = (u + 0x7FFFu + ((u >> 16) & 1u)) >> 16;  // RNE
    wt[(by * 32 + ty + i) * KD + bx * 32 + tx] = (uint16_t)r;
  }
}

// Weight-stationary one-barrier panel GEMM.
// Block: 64 output rows x all 512 cols, 4 waves. Phase 1: stage permuted
// 64x512 fp32 A-panel as bf16 into swizzled LDS (one barrier). Phase 2: per
// col-group cg (4 total), each wave burst-loads its 32-col x 512-K W-slice
// into 128 VGPRs (32x bf16x8, L2-resident wt), then runs a pure
// {ds_read_b128 -> mfma_32x32x16} x64 loop -- ZERO global loads and zero
// barriers inside the MFMA loop. A fetched from HBM exactly once.
__global__ __launch_bounds__(256, 2) void gemm_kernel(
    const float* __restrict__ x, const uint16_t* __restrict__ wt,
    float* __restrict__ out) {
  __shared__ uint16_t As[64 * 512];  // bf16, row stride 1024B, 16B-slot XOR swizzle

  const int tid = threadIdx.x;
  const int lane = tid & 63;
  const int l31 = lane & 31, hi = lane >> 5;
  const int wid = tid >> 6;
  const int m0 = blockIdx.x * 64;

  // ---- Phase 1: stage A-panel (permuted rows), fp32 -> bf16 LDS ----
  {
    const int r = tid >> 2;   // 0..63 output-local row
    const int c0 = tid & 3;   // 32B-chunk lane within row
    const int aRow = m0 + ((r & 31) << 1) + (r >> 5);  // perm folded in
    const char* src = (const char*)x + (size_t)aRow * (KD * 4) + c0 * 32;
    char* dst = (char*)As + r * 1024;
    const int rx = (r & 7) << 1;  // slot-XOR for this row
#pragma unroll 8
    for (int i = 0; i < 16; ++i) {
      const int c = c0 + i * 4;  // 16B bf16 slot index 0..63
      f32x4 lo = *(const f32x4*)(src + i * 128);
      f32x4 h4 = *(const f32x4*)(src + i * 128 + 16);
      u32x4 p = {pk_bf16(lo.x, lo.y), pk_bf16(lo.z, lo.w),
                 pk_bf16(h4.x, h4.y), pk_bf16(h4.z, h4.w)};
      *(u32x4*)(dst + (c ^ rx) * 16) = p;
    }
  }
  __syncthreads();  // the only barrier

  // ---- Phase 2: weight-stationary MFMA ----
  const char* wb = (const char*)wt;
  uint32_t aBase[2], aXor[2];
#pragma unroll
  for (int rg = 0; rg < 2; ++rg) {
    const int u = rg * 32 + l31;
    aBase[rg] = u * 1024;
    aXor[rg] = (u & 7) << 1;
  }

#pragma unroll 1
  for (int cg = 0; cg < 4; ++cg) {
    // burst-load this wave's 32-col W-slice for the full K into registers
    const uint32_t col = (uint32_t)(cg * 128 + wid * 32 + l31);
    const char* wp = wb + col * (KD * 2) + hi * 16;
    bf16x8 wreg[32];
#pragma unroll
    for (int ks = 0; ks < 32; ++ks)
      wreg[ks] = *(const bf16x8*)(wp + ks * 32);

#pragma unroll
    for (int rg = 0; rg < 2; ++rg) {
      f32x16 acc;
#pragma unroll
      for (int e = 0; e < 16; ++e) acc[e] = 0.f;
#pragma unroll
      for (int ks = 0; ks < 32; ++ks) {
        const uint32_t s = (uint32_t)(2 * ks + hi) ^ aXor[rg];
        bf16x8 af = *(const bf16x8*)((const char*)As + aBase[rg] + s * 16);
        acc = __builtin_amdgcn_mfma_f32_32x32x16_bf16(wreg[ks], af, acc, 0, 0, 0);
      }
      // D: col(lane&31)=x-row, row=(reg&3)+8*(reg>>2)+4*hi = W-col
      float* op = out + (size_t)(m0 + rg * 32 + l31) * ND + cg * 128 + wid * 32;
#pragma unroll
      for (int q = 0; q < 4; ++q) {
        f32x4 v = {acc[q * 4 + 0], acc[q * 4 + 1],
                   acc[q * 4 + 2], acc[q * 4 + 3]};
        *(f32x4*)(op + q * 8 + hi * 4) = v;
      }
    }
  }
}

extern "C" void kernel_launch(void* const* d_in, const int* in_sizes, int n_in,
                              void* d_out, int out_size, void* d_ws, size_t ws_size,
                              hipStream_t stream) {
  const float* x = (const float*)d_in[0];  // (32, 1024, 1024) fp32
  const float* w = (const float*)d_in[1];  // (512, 512) fp32
  float* out = (float*)d_out;              // (32, 2048, 512) fp32
  uint16_t* wt = (uint16_t*)d_ws;          // 512x512 bf16 = 512 KB scratch

  wt_kernel<<<dim3(16, 16), dim3(32, 8), 0, stream>>>(w, wt);
  gemm_kernel<<<dim3(1024), dim3(256), 0, stream>>>(x, wt, out);
}

// Round 7
// 293.504 us; speedup vs baseline: 1.0843x; 1.0843x over previous
//
#include <hip/hip_runtime.h>
#include <hip/hip_bf16.h>
#include <stdint.h>

typedef __attribute__((ext_vector_type(4))) float f32x4;
typedef __attribute__((ext_vector_type(16))) float f32x16;
typedef __attribute__((ext_vector_type(8))) short bf16x8;
typedef __attribute__((ext_vector_type(4))) uint32_t u32x4;

#define KD 512
#define ND 512

// pack two fp32 -> one u32 of two bf16 (round-half-away via +0x8000; v_perm
// grabs the high 16 bits of each)
__device__ __forceinline__ uint32_t pk_bf16(float lo, float hi) {
  uint32_t ulo = __float_as_uint(lo) + 0x8000u;
  uint32_t uhi = __float_as_uint(hi) + 0x8000u;
  return __builtin_amdgcn_perm(uhi, ulo, 0x07060302u);
}

// Transpose + RNE-convert w (512x512 fp32, w[k][d]) -> wt[d][k] bf16 in d_ws.
__global__ void wt_kernel(const float* __restrict__ w, uint16_t* __restrict__ wt) {
  __shared__ float tile[32][33];
  const int bx = blockIdx.x, by = blockIdx.y;
  const int tx = threadIdx.x, ty = threadIdx.y;  // (32, 8)
#pragma unroll
  for (int i = 0; i < 32; i += 8)
    tile[ty + i][tx] = w[(bx * 32 + ty + i) * ND + by * 32 + tx];
  __syncthreads();
#pragma unroll
  for (int i = 0; i < 32; i += 8) {
    uint32_t u = __float_as_uint(tile[tx][ty + i]);
    uint32_t r = (u + 0x7FFFu + ((u >> 16) & 1u)) >> 16;  // RNE
    wt[(by * 32 + ty + i) * KD + bx * 32 + tx] = (uint16_t)r;
  }
}

// One-barrier panel GEMM, high-TLP variant.
// Block: 512 threads (8 waves), 64 output rows x all 512 cols.
// Phase 1: stage permuted 64x512 fp32 A-panel as bf16 into swizzled LDS
//   (8 independent load->pack->ds_write chains per thread), ONE barrier.
// Phase 2: each wave owns 64 rows x 64 cols (2rg x 2tn of
//   mfma_f32_32x32x16_bf16); af from swizzled LDS; W-frags from L2-resident
//   wt via a depth-4 ring buffer (issue ks+3 at step ks). No global W burst
//   arrays (R5's spill), no per-step barriers (R1's drain).
// 64 KB LDS -> 2 blocks/CU -> 16 waves/CU. launch_bounds(512,4) caps 128 VGPR.
__global__ __launch_bounds__(512, 4) void gemm_kernel(
    const float* __restrict__ x, const uint16_t* __restrict__ wt,
    float* __restrict__ out) {
  __shared__ uint16_t As[64 * 512];  // bf16, row stride 1024B, 16B-slot XOR swizzle

  const int tid = threadIdx.x;
  const int lane = tid & 63;
  const int l31 = lane & 31, hi = lane >> 5;
  const int wid = tid >> 6;  // 0..7: col slice [wid*64, wid*64+64)
  const int m0 = blockIdx.x * 64;

  // ---- Phase 1: stage A-panel (permuted rows), fp32 -> bf16 LDS ----
  {
    const int r = tid >> 3;   // 0..63 output-local row
    const int c0 = tid & 7;   // 32B-chunk lane within row
    const int aRow = m0 + ((r & 31) << 1) + (r >> 5);  // perm folded in
    const char* src = (const char*)x + (size_t)aRow * (KD * 4) + c0 * 32;
    char* dst = (char*)As + r * 1024;
    const int rx = (r & 7) << 1;  // slot-XOR for this row
#pragma unroll
    for (int i = 0; i < 8; ++i) {
      const int c = c0 + i * 8;  // 16B bf16 slot index 0..63
      f32x4 lo = *(const f32x4*)(src + i * 256);
      f32x4 h4 = *(const f32x4*)(src + i * 256 + 16);
      u32x4 p = {pk_bf16(lo.x, lo.y), pk_bf16(lo.z, lo.w),
                 pk_bf16(h4.x, h4.y), pk_bf16(h4.z, h4.w)};
      *(u32x4*)(dst + (c ^ rx) * 16) = p;
    }
  }
  __syncthreads();  // the only barrier

  // ---- Phase 2: ring-buffered W, barrier-free MFMA ----
  const char* wb = (const char*)wt;
  uint32_t wOff[2];
#pragma unroll
  for (int tn = 0; tn < 2; ++tn)
    wOff[tn] = (uint32_t)(wid * 64 + tn * 32 + l31) * (KD * 2) + hi * 16;

  const uint32_t ax = (l31 & 7) << 1;  // A slot-XOR (row-group invariant)
  uint32_t aBase[2];
#pragma unroll
  for (int rg = 0; rg < 2; ++rg) aBase[rg] = (rg * 32 + l31) * 1024;

  f32x16 acc[2][2];
#pragma unroll
  for (int rg = 0; rg < 2; ++rg)
#pragma unroll
    for (int tn = 0; tn < 2; ++tn)
#pragma unroll
      for (int e = 0; e < 16; ++e) acc[rg][tn][e] = 0.f;

  bf16x8 wf[4][2];  // depth-4 ring, statically indexed (full unroll)
#pragma unroll
  for (int ks = 0; ks < 3; ++ks)
#pragma unroll
    for (int tn = 0; tn < 2; ++tn)
      wf[ks][tn] = *(const bf16x8*)(wb + wOff[tn] + ks * 32);

#pragma unroll
  for (int ks = 0; ks < 32; ++ks) {
    if (ks + 3 < 32) {
#pragma unroll
      for (int tn = 0; tn < 2; ++tn)
        wf[(ks + 3) & 3][tn] =
            *(const bf16x8*)(wb + wOff[tn] + (ks + 3) * 32);
    }
    bf16x8 af[2];
#pragma unroll
    for (int rg = 0; rg < 2; ++rg) {
      const uint32_t s = (uint32_t)(2 * ks + hi) ^ ax;
      af[rg] = *(const bf16x8*)((const char*)As + aBase[rg] + s * 16);
    }
#pragma unroll
    for (int rg = 0; rg < 2; ++rg)
#pragma unroll
      for (int tn = 0; tn < 2; ++tn)
        acc[rg][tn] = __builtin_amdgcn_mfma_f32_32x32x16_bf16(
            wf[ks & 3][tn], af[rg], acc[rg][tn], 0, 0, 0);
  }

  // ---- epilogue: D col(lane&31)=x-row, row=(reg&3)+8*(reg>>2)+4*hi=W-col ----
#pragma unroll
  for (int rg = 0; rg < 2; ++rg) {
    float* op = out + (size_t)(m0 + rg * 32 + l31) * ND + wid * 64;
#pragma unroll
    for (int tn = 0; tn < 2; ++tn) {
#pragma unroll
      for (int q = 0; q < 4; ++q) {
        f32x4 v = {acc[rg][tn][q * 4 + 0], acc[rg][tn][q * 4 + 1],
                   acc[rg][tn][q * 4 + 2], acc[rg][tn][q * 4 + 3]};
        *(f32x4*)(op + tn * 32 + q * 8 + hi * 4) = v;
      }
    }
  }
}

extern "C" void kernel_launch(void* const* d_in, const int* in_sizes, int n_in,
                              void* d_out, int out_size, void* d_ws, size_t ws_size,
                              hipStream_t stream) {
  const float* x = (const float*)d_in[0];  // (32, 1024, 1024) fp32
  const float* w = (const float*)d_in[1];  // (512, 512) fp32
  float* out = (float*)d_out;              // (32, 2048, 512) fp32
  uint16_t* wt = (uint16_t*)d_ws;          // 512x512 bf16 = 512 KB scratch

  wt_kernel<<<dim3(16, 16), dim3(32, 8), 0, stream>>>(w, wt);
  gemm_kernel<<<dim3(1024), dim3(512), 0, stream>>>(x, wt, out);
}

// Round 9
// 254.799 us; speedup vs baseline: 1.2490x; 1.1519x over previous
//
#include <hip/hip_runtime.h>
#include <hip/hip_bf16.h>
#include <stdint.h>

typedef __attribute__((ext_vector_type(4))) float f32x4;
typedef __attribute__((ext_vector_type(16))) float f32x16;
typedef __attribute__((ext_vector_type(8))) short bf16x8;
typedef __attribute__((ext_vector_type(4))) uint32_t u32x4;

#define KD 512
#define ND 512

// pack two fp32 -> one u32 of two bf16 (round-half-away via +0x8000; v_perm
// grabs the high 16 bits of each)
__device__ __forceinline__ uint32_t pk_bf16(float lo, float hi) {
  uint32_t ulo = __float_as_uint(lo) + 0x8000u;
  uint32_t uhi = __float_as_uint(hi) + 0x8000u;
  return __builtin_amdgcn_perm(uhi, ulo, 0x07060302u);
}

// Fragment-ready W repack: w (512x512 fp32, w[k][d]) -> wt chunks.
// 16B chunk (ks, d, hi) holds bf16 k = ks*16 + hi*8 + 0..7 of column d:
//   elem offset = ks*8192 + d*16 + hi*8 + j   (byte = ks*16384 + d*32 + hi*16 + j*2)
// => phase-2 wf load (fixed ks, 32 consecutive d, hi in lane>>5) is ONE
//    contiguous 1KB wave load (was a 32-line gather).
__global__ void wt_kernel(const float* __restrict__ w, uint16_t* __restrict__ wt) {
  __shared__ float tile[32][33];
  const int bx = blockIdx.x, by = blockIdx.y;
  const int tx = threadIdx.x, ty = threadIdx.y;  // (32, 8)
#pragma unroll
  for (int i = 0; i < 32; i += 8)
    tile[ty + i][tx] = w[(bx * 32 + ty + i) * ND + by * 32 + tx];
  __syncthreads();
#pragma unroll
  for (int i = 0; i < 32; i += 8) {
    uint32_t u = __float_as_uint(tile[tx][ty + i]);
    uint32_t r = (u + 0x7FFFu + ((u >> 16) & 1u)) >> 16;  // RNE
    const int d = by * 32 + ty + i;
    const int k = bx * 32 + tx;
    wt[((k >> 4) * 512 + d) * 16 + ((k >> 3) & 1) * 8 + (k & 7)] = (uint16_t)r;
  }
}

// One-barrier panel GEMM, high-TLP variant (R7) + fragment-ready W layout.
// Block: 512 threads (8 waves), 64 output rows x all 512 cols.
// Phase 1: stage permuted 64x512 fp32 A-panel as bf16 into swizzled LDS
//   (8 independent load->pack->ds_write chains per thread), ONE barrier.
// Phase 2: each wave owns 64 rows x 64 cols (2rg x 2tn of
//   mfma_f32_32x32x16_bf16); af from swizzled LDS; W-frags from L2-resident
//   wt via a depth-4 ring buffer -- now COALESCED 1KB loads per instruction.
// 64 KB LDS -> 2 blocks/CU -> 16 waves/CU. launch_bounds(512,4) caps 128 VGPR.
__global__ __launch_bounds__(512, 4) void gemm_kernel(
    const float* __restrict__ x, const uint16_t* __restrict__ wt,
    float* __restrict__ out) {
  __shared__ uint16_t As[64 * 512];  // bf16, row stride 1024B, 16B-slot XOR swizzle

  const int tid = threadIdx.x;
  const int lane = tid & 63;
  const int l31 = lane & 31, hi = lane >> 5;
  const int wid = tid >> 6;  // 0..7: col slice [wid*64, wid*64+64)
  const int m0 = blockIdx.x * 64;

  // ---- Phase 1: stage A-panel (permuted rows), fp32 -> bf16 LDS ----
  {
    const int r = tid >> 3;   // 0..63 output-local row
    const int c0 = tid & 7;   // 32B-chunk lane within row
    const int aRow = m0 + ((r & 31) << 1) + (r >> 5);  // perm folded in
    const char* src = (const char*)x + (size_t)aRow * (KD * 4) + c0 * 32;
    char* dst = (char*)As + r * 1024;
    const int rx = (r & 7) << 1;  // slot-XOR for this row
#pragma unroll
    for (int i = 0; i < 8; ++i) {
      const int c = c0 + i * 8;  // 16B bf16 slot index 0..63
      f32x4 lo = *(const f32x4*)(src + i * 256);
      f32x4 h4 = *(const f32x4*)(src + i * 256 + 16);
      u32x4 p = {pk_bf16(lo.x, lo.y), pk_bf16(lo.z, lo.w),
                 pk_bf16(h4.x, h4.y), pk_bf16(h4.z, h4.w)};
      *(u32x4*)(dst + (c ^ rx) * 16) = p;
    }
  }
  __syncthreads();  // the only barrier

  // ---- Phase 2: ring-buffered W (coalesced frag loads), barrier-free MFMA ----
  const char* wb = (const char*)wt;
  uint32_t wOff[2];  // lane offset within a 16KB ks-block
#pragma unroll
  for (int tn = 0; tn < 2; ++tn)
    wOff[tn] = (uint32_t)(wid * 64 + tn * 32 + l31) * 32 + hi * 16;

  const uint32_t ax = (l31 & 7) << 1;  // A slot-XOR (row-group invariant)
  uint32_t aBase[2];
#pragma unroll
  for (int rg = 0; rg < 2; ++rg) aBase[rg] = (rg * 32 + l31) * 1024;

  f32x16 acc[2][2];
#pragma unroll
  for (int rg = 0; rg < 2; ++rg)
#pragma unroll
    for (int tn = 0; tn < 2; ++tn)
#pragma unroll
      for (int e = 0; e < 16; ++e) acc[rg][tn][e] = 0.f;

  bf16x8 wf[4][2];  // depth-4 ring, statically indexed (full unroll)
#pragma unroll
  for (int ks = 0; ks < 3; ++ks)
#pragma unroll
    for (int tn = 0; tn < 2; ++tn)
      wf[ks][tn] = *(const bf16x8*)(wb + ks * 16384 + wOff[tn]);

#pragma unroll
  for (int ks = 0; ks < 32; ++ks) {
    if (ks + 3 < 32) {
#pragma unroll
      for (int tn = 0; tn < 2; ++tn)
        wf[(ks + 3) & 3][tn] =
            *(const bf16x8*)(wb + (ks + 3) * 16384 + wOff[tn]);
    }
    bf16x8 af[2];
#pragma unroll
    for (int rg = 0; rg < 2; ++rg) {
      const uint32_t s = (uint32_t)(2 * ks + hi) ^ ax;
      af[rg] = *(const bf16x8*)((const char*)As + aBase[rg] + s * 16);
    }
#pragma unroll
    for (int rg = 0; rg < 2; ++rg)
#pragma unroll
      for (int tn = 0; tn < 2; ++tn)
        acc[rg][tn] = __builtin_amdgcn_mfma_f32_32x32x16_bf16(
            wf[ks & 3][tn], af[rg], acc[rg][tn], 0, 0, 0);
  }

  // ---- epilogue: D col(lane&31)=x-row, row=(reg&3)+8*(reg>>2)+4*hi=W-col ----
#pragma unroll
  for (int rg = 0; rg < 2; ++rg) {
    float* op = out + (size_t)(m0 + rg * 32 + l31) * ND + wid * 64;
#pragma unroll
    for (int tn = 0; tn < 2; ++tn) {
#pragma unroll
      for (int q = 0; q < 4; ++q) {
        f32x4 v = {acc[rg][tn][q * 4 + 0], acc[rg][tn][q * 4 + 1],
                   acc[rg][tn][q * 4 + 2], acc[rg][tn][q * 4 + 3]};
        *(f32x4*)(op + tn * 32 + q * 8 + hi * 4) = v;
      }
    }
  }
}

extern "C" void kernel_launch(void* const* d_in, const int* in_sizes, int n_in,
                              void* d_out, int out_size, void* d_ws, size_t ws_size,
                              hipStream_t stream) {
  const float* x = (const float*)d_in[0];  // (32, 1024, 1024) fp32
  const float* w = (const float*)d_in[1];  // (512, 512) fp32
  float* out = (float*)d_out;              // (32, 2048, 512) fp32
  uint16_t* wt = (uint16_t*)d_ws;          // 512KB bf16 fragment-layout scratch

  wt_kernel<<<dim3(16, 16), dim3(32, 8), 0, stream>>>(w, wt);
  gemm_kernel<<<dim3(1024), dim3(512), 0, stream>>>(x, wt, out);
}